// Round 7
// baseline (367.574 us; speedup 1.0000x reference)
//
#include <hip/hip_runtime.h>
#include <math.h>

#define T_SEQ  2048
#define DMODEL 2048
#define NHEADS 16
#define HDIM   128
#define MROWS  4096   // B*T

typedef __attribute__((ext_vector_type(8)))  __bf16 bf16x8;
typedef __attribute__((ext_vector_type(4)))  __bf16 bf16x4;
typedef __attribute__((ext_vector_type(4)))  float  f32x4;
typedef __attribute__((ext_vector_type(16))) float  f32x16;

#define GLOBAL_AS __attribute__((address_space(1)))
#define LDS_AS    __attribute__((address_space(3)))
__device__ __forceinline__ void async_copy16(const __bf16* g, __bf16* l) {
  // 16B/lane, LDS dest = wave-uniform base + lane*16 (m97/m104 semantics)
  __builtin_amdgcn_global_load_lds((const GLOBAL_AS void*)g, (LDS_AS void*)l, 16, 0, 0);
}

// ---------------------------------------------------------------------------
// RoPE table: rope[pos*64+d] = {cos, sin}. fp64 trig (one-time, 131k entries).
// ---------------------------------------------------------------------------
__global__ void build_rope_kernel(float2* __restrict__ rope) {
  int idx = blockIdx.x * blockDim.x + threadIdx.x;   // 2048*64
  int d = idx & 63, pos = idx >> 6;
  double freq = pow(10000.0, -(double)d / 64.0);
  double ang = (double)pos * freq;
  rope[idx] = make_float2((float)cos(ang), (float)sin(ang));
}

// ---------------------------------------------------------------------------
// fp32 -> bf16 cast
// ---------------------------------------------------------------------------
__global__ void cast_bf16_kernel(const float* __restrict__ in,
                                 __bf16* __restrict__ out, int n4) {
  int i = blockIdx.x * blockDim.x + threadIdx.x;
  if (i >= n4) return;
  float4 v = ((const float4*)in)[i];
  bf16x4 o = { (__bf16)v.x, (__bf16)v.y, (__bf16)v.z, (__bf16)v.w };
  *(bf16x4*)(out + (size_t)i*4) = o;
}

// ---------------------------------------------------------------------------
// Combined weight transpose-cast: Wq|Wk|Wv -> wqkvt [2304][2048],
// Wo -> wot [2048][2048]. One launch, region by blockIdx.x.
// ---------------------------------------------------------------------------
__global__ void wtrans_kernel(const float* __restrict__ Wq,
                              const float* __restrict__ Wk,
                              const float* __restrict__ Wv,
                              const float* __restrict__ Wo,
                              __bf16* __restrict__ wqkvt,
                              __bf16* __restrict__ wot) {
  __shared__ float t[32][33];
  const int bx = blockIdx.x;            // 0..135
  const float* src; __bf16* dst; int istride, c0, orow;
  if (bx < 64)       { src = Wq; istride = 2048; c0 = bx*32;      orow = c0;        dst = wqkvt; }
  else if (bx < 68)  { src = Wk; istride = 128;  c0 = (bx-64)*32; orow = 2048 + c0; dst = wqkvt; }
  else if (bx < 72)  { src = Wv; istride = 128;  c0 = (bx-68)*32; orow = 2176 + c0; dst = wqkvt; }
  else               { src = Wo; istride = 2048; c0 = (bx-72)*32; orow = c0;        dst = wot; }
  const int tx = threadIdx.x & 31, ty = threadIdx.x >> 5;
  const int r0 = blockIdx.y*32;
#pragma unroll
  for (int i = 0; i < 4; ++i)
    t[ty + i*8][tx] = src[(size_t)(r0 + ty + i*8)*istride + c0 + tx];
  __syncthreads();
#pragma unroll
  for (int i = 0; i < 4; ++i)
    dst[(size_t)(orow + ty + i*8)*2048 + r0 + tx] = (__bf16)t[tx][ty + i*8];
}

// ---------------------------------------------------------------------------
// Fused QKV GEMM: C = x @ [Wq|Wk|Wv] + bias, epilogue does RoPE (Q,K) +
// scale (Q) + bf16 cast, register-resident (column remap puts the RoPE pair
// (d, d+64) in the same lane). V-blocks write V^T [B][128][T] DIRECTLY
// (packed bf16x4 over 4 consecutive t) — no separate transpose kernel.
// grid (18, 32): bx 0..15 = Q head bx; bx 16 = K; bx 17 = V.
// ---------------------------------------------------------------------------
__global__ __launch_bounds__(256) void gemm_qkv_fused(
    const __bf16* __restrict__ A,      // xb [4096][2048]
    const __bf16* __restrict__ Bt,     // wqkvt [2304][2048]
    const float* __restrict__ bq, const float* __restrict__ bk,
    const float* __restrict__ bv,
    const float2* __restrict__ rope,   // [2048][64]
    __bf16* __restrict__ qrb,          // [4096][2048]
    __bf16* __restrict__ kbb,          // [4096][128]
    __bf16* __restrict__ vtb,          // [B][128][T] (V^T)
    float qscale)
{
  __shared__ __bf16 As[128*32];
  __shared__ __bf16 Bs[128*32];
  const int tid = threadIdx.x;
  const int lane = tid & 63, wave = tid >> 6;
  const int quad = lane >> 4, l16 = lane & 15;
  const int m0 = (wave >> 1)*64, n0 = (wave & 1)*32;
  const int row0 = blockIdx.y*128, col0 = blockIdx.x*128;
  const int srow = lane >> 2, scol = (lane & 3)*8;

  f32x4 acc[4][4];
#pragma unroll
  for (int i = 0; i < 4; ++i)
#pragma unroll
    for (int j = 0; j < 4; ++j) acc[i][j] = (f32x4){0.f,0.f,0.f,0.f};

  const __bf16* Ag = A  + (size_t)(row0 + wave*32 + srow)*DMODEL + scol;
  const __bf16* Bg = Bt + (size_t)(col0 + wave*32 + srow)*DMODEL + scol;
  __bf16* AsW = &As[wave*1024];
  __bf16* BsW = &Bs[wave*1024];

  for (int kk = 0; kk < DMODEL; kk += 32) {
    __syncthreads();
    async_copy16(Ag + kk,                     AsW);
    async_copy16(Ag + kk + (size_t)16*DMODEL, AsW + 512);
    async_copy16(Bg + kk,                     BsW);
    async_copy16(Bg + kk + (size_t)16*DMODEL, BsW + 512);
    __syncthreads();
    bf16x8 af[4], bfr[4];
#pragma unroll
    for (int i = 0; i < 4; ++i)
      af[i] = *(const bf16x8*)&As[(m0 + i*16 + l16)*32 + quad*8];
#pragma unroll
    for (int j = 0; j < 4; ++j) {
      const int cb = n0 + (j & 1)*16 + (j >> 1)*64;   // remapped column base
      bfr[j] = *(const bf16x8*)&Bs[(cb + l16)*32 + quad*8];
    }
#pragma unroll
    for (int i = 0; i < 4; ++i)
#pragma unroll
      for (int j = 0; j < 4; ++j)
        acc[i][j] = __builtin_amdgcn_mfma_f32_16x16x32_bf16(af[i], bfr[j], acc[i][j], 0,0,0);
  }

  // ---- fused epilogue ------------------------------------------------------
  const int bx = blockIdx.x;
  if (bx < 17) {
    // Q (bx<16) and K (bx==16): RoPE + (Q) scale, row-major bf16 store
    const float* bias_p; float scale; __bf16* obase; int ostride;
    if (bx < 16) { bias_p = bq + bx*128; scale = qscale; obase = qrb + bx*128; ostride = 2048; }
    else         { bias_p = bk;          scale = 1.f;    obase = kbb;          ostride = 128; }
#pragma unroll
    for (int j = 0; j < 2; ++j) {
      const int d = n0 + j*16 + l16;        // 0..63 within the 128-wide region
      const float b1 = bias_p[d], b2 = bias_p[d + 64];
#pragma unroll
      for (int i = 0; i < 4; ++i) {
        const int rl = m0 + i*16 + quad*4;
#pragma unroll
        for (int r = 0; r < 4; ++r) {
          const int rg = row0 + rl + r;
          const float x1 = acc[i][j][r]   + b1;
          const float x2 = acc[i][j+2][r] + b2;
          float2 cs = rope[(size_t)(rg & (T_SEQ-1))*64 + d];
          obase[(size_t)rg*ostride + d]      = (__bf16)((x1*cs.x - x2*cs.y)*scale);
          obase[(size_t)rg*ostride + d + 64] = (__bf16)((x2*cs.x + x1*cs.y)*scale);
        }
      }
    }
  } else {
    // V: write transposed [B][128][T]; 4 consecutive r -> 4 consecutive t
    const int bb = row0 >> 11;              // batch (block never straddles)
    const int tb = row0 & (T_SEQ - 1);
    __bf16* vb = vtb + (size_t)bb*HDIM*T_SEQ;
#pragma unroll
    for (int j = 0; j < 2; ++j) {
      const int d = n0 + j*16 + l16;
      const float b1 = bv[d], b2 = bv[d + 64];
#pragma unroll
      for (int i = 0; i < 4; ++i) {
        const int t0 = tb + m0 + i*16 + quad*4;
        bf16x4 lo = { (__bf16)(acc[i][j][0]+b1),   (__bf16)(acc[i][j][1]+b1),
                      (__bf16)(acc[i][j][2]+b1),   (__bf16)(acc[i][j][3]+b1) };
        bf16x4 hi = { (__bf16)(acc[i][j+2][0]+b2), (__bf16)(acc[i][j+2][1]+b2),
                      (__bf16)(acc[i][j+2][2]+b2), (__bf16)(acc[i][j+2][3]+b2) };
        *(bf16x4*)&vb[(size_t)d*T_SEQ + t0]        = lo;
        *(bf16x4*)&vb[(size_t)(d + 64)*T_SEQ + t0] = hi;
      }
    }
  }
}

// ---------------------------------------------------------------------------
// m97-style bf16 MFMA GEMM: C = A@B + bias, fp32 out (O projection).
// ---------------------------------------------------------------------------
__global__ __launch_bounds__(256) void gemm_bf16_t128(
    const __bf16* __restrict__ A, const __bf16* __restrict__ Bt,
    const float* __restrict__ bias, float* __restrict__ C,
    int M, int N, int K)
{
  __shared__ __bf16 As[128*32];
  __shared__ __bf16 Bs[128*32];
  const int tid = threadIdx.x;
  const int lane = tid & 63, wave = tid >> 6;
  const int quad = lane >> 4, l16 = lane & 15;
  const int m0 = (wave & 1)*64, n0 = (wave >> 1)*64;
  const int row0 = blockIdx.y*128, col0 = blockIdx.x*128;
  const int srow = lane >> 2, scol = (lane & 3)*8;

  f32x4 acc[4][4];
#pragma unroll
  for (int i = 0; i < 4; ++i)
#pragma unroll
    for (int j = 0; j < 4; ++j) acc[i][j] = (f32x4){0.f,0.f,0.f,0.f};

  const __bf16* Ag = A  + (size_t)(row0 + wave*32 + srow)*K + scol;
  const __bf16* Bg = Bt + (size_t)(col0 + wave*32 + srow)*K + scol;
  __bf16* AsW = &As[wave*1024];
  __bf16* BsW = &Bs[wave*1024];

  for (int kk = 0; kk < K; kk += 32) {
    __syncthreads();
    async_copy16(Ag + kk,              AsW);
    async_copy16(Ag + kk + (size_t)16*K, AsW + 512);
    async_copy16(Bg + kk,              BsW);
    async_copy16(Bg + kk + (size_t)16*K, BsW + 512);
    __syncthreads();
    bf16x8 af[4], bfr[4];
#pragma unroll
    for (int i = 0; i < 4; ++i)
      af[i] = *(const bf16x8*)&As[(m0 + i*16 + l16)*32 + quad*8];
#pragma unroll
    for (int j = 0; j < 4; ++j)
      bfr[j] = *(const bf16x8*)&Bs[(n0 + j*16 + l16)*32 + quad*8];
#pragma unroll
    for (int i = 0; i < 4; ++i)
#pragma unroll
      for (int j = 0; j < 4; ++j)
        acc[i][j] = __builtin_amdgcn_mfma_f32_16x16x32_bf16(af[i], bfr[j], acc[i][j], 0,0,0);
  }
#pragma unroll
  for (int j = 0; j < 4; ++j) {
    const int ccol = col0 + n0 + j*16 + l16;
    const float bvv = bias[ccol];
#pragma unroll
    for (int i = 0; i < 4; ++i) {
      const int crow = row0 + m0 + i*16 + quad*4;
#pragma unroll
      for (int r = 0; r < 4; ++r)
        C[(size_t)(crow + r)*N + ccol] = acc[i][j][r] + bvv;
    }
  }
}

// ---------------------------------------------------------------------------
// MFMA flash MQA attention, O^T = V^T·P^T with in-register P^T (R5 swizzle)
// + R6 4-chain ILP + R7 single-barrier DOUBLE-BUFFERED LDS:
// store prefetched tile t+1 into buf[1^cur] before computing tile t from
// buf[cur]; one __syncthreads per tile (was 2 + full drain).
// grid = (T/128, H, B); 2 blocks/CU (LDS 71.7 KB/block).
// ---------------------------------------------------------------------------
#define KSTR 136
#define VSTR 72
__global__ __launch_bounds__(256) void mqa_attn_mfma(
    const __bf16* __restrict__ qb,   // [B*T][2048] rotated+scaled bf16
    const __bf16* __restrict__ kb,   // [B*T][128]  rotated bf16
    const __bf16* __restrict__ vt,   // [B][128][T] bf16 (V^T)
    __bf16* __restrict__ ctx)        // [B*T][2048] bf16
{
  __shared__ __bf16 Ks[2][64*KSTR];     // 2 x 17408 B
  __shared__ __bf16 Vs[2][128*VSTR];    // 2 x 18432 B
  const int tid = threadIdx.x, lane = tid & 63, wave = tid >> 6;
  const int h5 = lane >> 5, l32 = lane & 31;
  // swap bits 2<->3 of l32: aligns S^T C-layout with P^T B-operand layout
  const int swr = (l32 & 19) | ((l32 & 4) << 1) | ((l32 & 8) >> 1);
  const int h = blockIdx.y, b = blockIdx.z;
  const int qbase = blockIdx.x*128 + wave*32;

  // Q as B-operand fragments: B[k=h5*8+j][n=l32] = Q[q=l32][d=ds*16+h5*8+j]
  bf16x8 qf[8];
  const __bf16* qp = qb + ((size_t)b*T_SEQ + qbase + l32)*DMODEL + h*HDIM;
#pragma unroll
  for (int ds = 0; ds < 8; ++ds) qf[ds] = *(const bf16x8*)(qp + ds*16 + h5*8);

  f32x16 oacc[4];
#pragma unroll
  for (int g = 0; g < 4; ++g)
#pragma unroll
    for (int r = 0; r < 16; ++r) oacc[g][r] = 0.f;
  float lsum4[4] = {0.f, 0.f, 0.f, 0.f};

  const __bf16* kbase = kb + (size_t)b*T_SEQ*HDIM;
  const __bf16* vbase = vt + (size_t)b*HDIM*T_SEQ;

  // per-thread staging chunk coordinates
  // K: chunk i*256+tid -> key=idx>>4, col=(idx&15)*8
  // V: chunk i*256+tid -> d  =idx>>3, col=(idx&7)*8
  bf16x8 kreg[4], vreg[4];
#pragma unroll
  for (int i = 0; i < 4; ++i) {               // load tile 0
    int idx = i*256 + tid;
    kreg[i] = *(const bf16x8*)(kbase + (size_t)(idx >> 4)*HDIM + (idx & 15)*8);
    vreg[i] = *(const bf16x8*)(vbase + (size_t)(idx >> 3)*T_SEQ + (idx & 7)*8);
  }
#pragma unroll
  for (int i = 0; i < 4; ++i) {               // store tile 0 -> buf0
    int idx = i*256 + tid;
    *(bf16x8*)&Ks[0][(idx >> 4)*KSTR + (idx & 15)*8] = kreg[i];
    *(bf16x8*)&Vs[0][(idx >> 3)*VSTR + (idx & 7)*8]  = vreg[i];
  }
#pragma unroll
  for (int i = 0; i < 4; ++i) {               // load tile 1
    int idx = i*256 + tid;
    kreg[i] = *(const bf16x8*)(kbase + (size_t)(64 + (idx >> 4))*HDIM + (idx & 15)*8);
    vreg[i] = *(const bf16x8*)(vbase + (size_t)(idx >> 3)*T_SEQ + 64 + (idx & 7)*8);
  }
  __syncthreads();

  constexpr int NT = T_SEQ/64;
  for (int kt = 0; kt < NT; ++kt) {
    const int cur = kt & 1;
    // store prefetched tile kt+1 into the other buffer (protected by the
    // barrier at the end of iteration kt-1)
    if (kt + 1 < NT) {
#pragma unroll
      for (int i = 0; i < 4; ++i) {
        int idx = i*256 + tid;
        *(bf16x8*)&Ks[1^cur][(idx >> 4)*KSTR + (idx & 15)*8] = kreg[i];
        *(bf16x8*)&Vs[1^cur][(idx >> 3)*VSTR + (idx & 7)*8]  = vreg[i];
      }
    }
    // prefetch tile kt+2 (global -> regs), hides under compute
    if (kt + 2 < NT) {
      const int kn = (kt + 2)*64;
#pragma unroll
      for (int i = 0; i < 4; ++i) {
        int idx = i*256 + tid;
        kreg[i] = *(const bf16x8*)(kbase + (size_t)(kn + (idx >> 4))*HDIM + (idx & 15)*8);
        vreg[i] = *(const bf16x8*)(vbase + (size_t)(idx >> 3)*T_SEQ + kn + (idx & 7)*8);
      }
    }

    // ---- S phase: 4 independent chains of 4 dependent MFMAs ----
    f32x16 s_lo[2], s_hi[2];
#pragma unroll
    for (int kg = 0; kg < 2; ++kg)
#pragma unroll
      for (int r = 0; r < 16; ++r) { s_lo[kg][r] = 0.f; s_hi[kg][r] = 0.f; }
#pragma unroll
    for (int ds = 0; ds < 4; ++ds) {
      bf16x8 k00 = *(const bf16x8*)&Ks[cur][swr*KSTR      + ds*16 + h5*8];
      bf16x8 k01 = *(const bf16x8*)&Ks[cur][(32+swr)*KSTR + ds*16 + h5*8];
      bf16x8 k10 = *(const bf16x8*)&Ks[cur][swr*KSTR      + (ds+4)*16 + h5*8];
      bf16x8 k11 = *(const bf16x8*)&Ks[cur][(32+swr)*KSTR + (ds+4)*16 + h5*8];
      s_lo[0] = __builtin_amdgcn_mfma_f32_32x32x16_bf16(k00, qf[ds],   s_lo[0], 0,0,0);
      s_lo[1] = __builtin_amdgcn_mfma_f32_32x32x16_bf16(k01, qf[ds],   s_lo[1], 0,0,0);
      s_hi[0] = __builtin_amdgcn_mfma_f32_32x32x16_bf16(k10, qf[ds+4], s_hi[0], 0,0,0);
      s_hi[1] = __builtin_amdgcn_mfma_f32_32x32x16_bf16(k11, qf[ds+4], s_hi[1], 0,0,0);
    }

    // ---- exp2 -> P^T B-operand fragments, in-register ----
    bf16x8 pf[2][2];
#pragma unroll
    for (int kg = 0; kg < 2; ++kg)
#pragma unroll
      for (int r = 0; r < 16; ++r) {
        float p = __builtin_amdgcn_exp2f(s_lo[kg][r] + s_hi[kg][r]);
        lsum4[r & 3] += p;
        pf[kg][r >> 3][r & 7] = (__bf16)p;
      }

    // ---- O phase: 4 independent oacc chains ----
#pragma unroll
    for (int kg = 0; kg < 2; ++kg)
#pragma unroll
      for (int ks = 0; ks < 2; ++ks) {
#pragma unroll
        for (int g = 0; g < 4; ++g) {
          bf16x8 vf = *(const bf16x8*)&Vs[cur][(g*32 + l32)*VSTR + kg*32 + ks*16 + h5*8];
          oacc[g] = __builtin_amdgcn_mfma_f32_32x32x16_bf16(vf, pf[kg][ks], oacc[g], 0,0,0);
        }
      }
    __syncthreads();   // all waves done reading buf[cur] & writing buf[1^cur]
  }

  // lane owns query l32; combine partial sums + the two h5 halves
  float lsum = (lsum4[0] + lsum4[1]) + (lsum4[2] + lsum4[3]);
  lsum += __shfl_xor(lsum, 32);
  const float inv = 1.f / lsum;

  // O^T C-layout: d = g*32 + rq*8 + h5*4 + (reg&3)  -> packed bf16x4 stores
  __bf16* op = ctx + ((size_t)b*T_SEQ + qbase + l32)*DMODEL + h*HDIM;
#pragma unroll
  for (int g = 0; g < 4; ++g)
#pragma unroll
    for (int rq = 0; rq < 4; ++rq) {
      const int d = g*32 + rq*8 + h5*4;
      bf16x4 ov = { (__bf16)(oacc[g][rq*4+0]*inv), (__bf16)(oacc[g][rq*4+1]*inv),
                    (__bf16)(oacc[g][rq*4+2]*inv), (__bf16)(oacc[g][rq*4+3]*inv) };
      *(bf16x4*)&op[d] = ov;
    }
}

// ---------------------------------------------------------------------------
extern "C" void kernel_launch(void* const* d_in, const int* in_sizes, int n_in,
                              void* d_out, int out_size, void* d_ws, size_t ws_size,
                              hipStream_t stream) {
  const float* x  = (const float*)d_in[0];
  const float* Wq = (const float*)d_in[1];
  const float* bq = (const float*)d_in[2];
  const float* Wk = (const float*)d_in[3];
  const float* bk = (const float*)d_in[4];
  const float* Wv = (const float*)d_in[5];
  const float* bv = (const float*)d_in[6];
  const float* Wo = (const float*)d_in[7];
  const float* bo = (const float*)d_in[8];
  float* out = (float*)d_out;

  uint8_t* ws = (uint8_t*)d_ws;
  __bf16* qrb  = (__bf16*)(ws);              // 16.78 MB rotated+scaled Q bf16
  __bf16* xb   = (__bf16*)(ws + 16777216);   // 16.78 MB x bf16; later ctx bf16
  __bf16* wqkvt= (__bf16*)(ws + 33554432);   //  9.44 MB [2304][2048]
  __bf16* wot  = (__bf16*)(ws + 42991616);   //  8.39 MB [2048][2048]
  __bf16* kbb  = (__bf16*)(ws + 51380224);   //  1.05 MB rotated K bf16
  __bf16* vtb  = (__bf16*)(ws + 52428800);   //  1.05 MB V^T bf16 [B][128][T]
  float2* rope = (float2*)(ws + 53477376);   //  1.05 MB cos/sin table

  const float qscale = 1.4426950408889634f * 0.08838834764831845f; // log2e/sqrt(128)

  build_rope_kernel<<<512, 256, 0, stream>>>(rope);
  wtrans_kernel<<<dim3(136,64), 256, 0, stream>>>(Wq, Wk, Wv, Wo, wqkvt, wot);
  cast_bf16_kernel<<<8192, 256, 0, stream>>>(x, xb, MROWS*DMODEL/4);

  // writes qrb (rotated+scaled Q), kbb (rotated K), vtb (V^T) directly
  gemm_qkv_fused<<<dim3(18,32), 256, 0, stream>>>(
      xb, wqkvt, bq, bk, bv, rope, qrb, kbb, vtb, qscale);

  // attention reads qrb/kbb/vtb, writes bf16 ctx over xb (x is dead)
  mqa_attn_mfma<<<dim3(16,16,2), 256, 0, stream>>>(qrb, kbb, vtb, xb);

  gemm_bf16_t128<<<dim3(16,32), 256, 0, stream>>>(xb, wot, bo, out, MROWS, DMODEL, DMODEL);
}